// Round 8
// baseline (126.270 us; speedup 1.0000x reference)
//
#include <hip/hip_runtime.h>
#include <math.h>

#define BSZ 4096
#define NTOK 8192
#define NVEC (BSZ * NTOK / 4)   // 2^23 float4s

#define NBLOCKS 8192
#define NTHREADS 256
#define PER_BLOCK (NVEC / NBLOCKS)   // 1024 float4s per stream per block
#define UNROLL 4

typedef float f32x4 __attribute__((ext_vector_type(4)));

__global__ __launch_bounds__(NTHREADS) void gauss_nll_onepass(
    const float4* __restrict__ mu,
    const float4* __restrict__ sigma,
    const float4* __restrict__ ty,
    float* __restrict__ out) {
    int base = blockIdx.x * PER_BLOCK + threadIdx.x;

    f32x4 m[UNROLL];
    float4 s[UNROLL], t[UNROLL];
    const f32x4* mu_nt = (const f32x4*)mu;
#pragma unroll
    for (int j = 0; j < UNROLL; ++j)
        m[j] = __builtin_nontemporal_load(&mu_nt[base + j * NTHREADS]);
#pragma unroll
    for (int j = 0; j < UNROLL; ++j) s[j] = sigma[base + j * NTHREADS];
#pragma unroll
    for (int j = 0; j < UNROLL; ++j) t[j] = ty[base + j * NTHREADS];

    float acc = 0.0f;
#pragma unroll
    for (int j = 0; j < UNROLL; ++j) {
        float d0 = t[j].x - m[j].x;
        float d1 = t[j].y - m[j].y;
        float d2 = t[j].z - m[j].z;
        float d3 = t[j].w - m[j].w;
        float r0 = __logf(s[j].x) + d0 * d0 * __builtin_amdgcn_rcpf(s[j].x);
        float r1 = __logf(s[j].y) + d1 * d1 * __builtin_amdgcn_rcpf(s[j].y);
        float r2 = __logf(s[j].z) + d2 * d2 * __builtin_amdgcn_rcpf(s[j].z);
        float r3 = __logf(s[j].w) + d3 * d3 * __builtin_amdgcn_rcpf(s[j].w);
        acc += (r0 + r1) + (r2 + r3);
    }

    // wave-64 butterfly reduce
    for (int off = 32; off > 0; off >>= 1)
        acc += __shfl_down(acc, off, 64);

    __shared__ float wsum[NTHREADS / 64];
    int lane = threadIdx.x & 63;
    int wid = threadIdx.x >> 6;
    if (lane == 0) wsum[wid] = acc;
    __syncthreads();
    if (threadIdx.x == 0) {
        float bpart = (wsum[0] + wsum[1]) + (wsum[2] + wsum[3]);
        // contribution to 0.5*(NT*log2pi + total/BS); constant added by block 0
        float contrib = bpart * (0.5f / (float)BSZ);
        if (blockIdx.x == 0) {
            const float log2pi = 1.8378770664093453f;
            contrib += 0.5f * (float)NTOK * log2pi;
        }
        atomicAdd(out, contrib);  // one device-scope atomic per block
    }
}

extern "C" void kernel_launch(void* const* d_in, const int* in_sizes, int n_in,
                              void* d_out, int out_size, void* d_ws, size_t ws_size,
                              hipStream_t stream) {
    const float4* mu = (const float4*)d_in[0];
    const float4* sigma = (const float4*)d_in[1];
    const float4* ty = (const float4*)d_in[2];
    float* out = (float*)d_out;

    // out[0] accumulates atomically; zero it each call (graph-capture legal)
    hipMemsetAsync(out, 0, sizeof(float), stream);
    gauss_nll_onepass<<<NBLOCKS, NTHREADS, 0, stream>>>(mu, sigma, ty, out);
}

// Round 9
// 67.573 us; speedup vs baseline: 1.8686x; 1.8686x over previous
//
#include <hip/hip_runtime.h>
#include <math.h>

#define BSZ 4096
#define NTOK 8192
#define NVEC (BSZ * NTOK / 4)   // 2^23 float4s

#define NBLOCKS 8192
#define NTHREADS 256
#define PER_BLOCK (NVEC / NBLOCKS)   // 1024 float4s per stream per block
#define UNROLL 4

typedef float f32x4 __attribute__((ext_vector_type(4)));

__global__ __launch_bounds__(NTHREADS) void gauss_nll_partial(
    const float4* __restrict__ mu,
    const float4* __restrict__ sigma,
    const float4* __restrict__ ty,
    float* __restrict__ partials) {
    int base = blockIdx.x * PER_BLOCK + threadIdx.x;

    f32x4 m[UNROLL];
    float4 s[UNROLL], t[UNROLL];
    // mu streamed with the nt bit: -7% measured (R7) vs plain loads.
    const f32x4* mu_nt = (const f32x4*)mu;
#pragma unroll
    for (int j = 0; j < UNROLL; ++j)
        m[j] = __builtin_nontemporal_load(&mu_nt[base + j * NTHREADS]);
#pragma unroll
    for (int j = 0; j < UNROLL; ++j) s[j] = sigma[base + j * NTHREADS];
#pragma unroll
    for (int j = 0; j < UNROLL; ++j) t[j] = ty[base + j * NTHREADS];

    float acc = 0.0f;
#pragma unroll
    for (int j = 0; j < UNROLL; ++j) {
        float d0 = t[j].x - m[j].x;
        float d1 = t[j].y - m[j].y;
        float d2 = t[j].z - m[j].z;
        float d3 = t[j].w - m[j].w;
        float r0 = __logf(s[j].x) + d0 * d0 * __builtin_amdgcn_rcpf(s[j].x);
        float r1 = __logf(s[j].y) + d1 * d1 * __builtin_amdgcn_rcpf(s[j].y);
        float r2 = __logf(s[j].z) + d2 * d2 * __builtin_amdgcn_rcpf(s[j].z);
        float r3 = __logf(s[j].w) + d3 * d3 * __builtin_amdgcn_rcpf(s[j].w);
        acc += (r0 + r1) + (r2 + r3);
    }

    // wave-64 butterfly reduce
    for (int off = 32; off > 0; off >>= 1)
        acc += __shfl_down(acc, off, 64);

    __shared__ float wsum[NTHREADS / 64];
    int lane = threadIdx.x & 63;
    int wid = threadIdx.x >> 6;
    if (lane == 0) wsum[wid] = acc;
    __syncthreads();
    if (threadIdx.x == 0) {
        partials[blockIdx.x] = wsum[0] + wsum[1] + wsum[2] + wsum[3];
    }
}

__global__ __launch_bounds__(1024) void gauss_nll_final(
    const float* __restrict__ partials, float* __restrict__ out) {
    float acc = 0.0f;
    for (int i = threadIdx.x; i < NBLOCKS; i += 1024)
        acc += partials[i];
    for (int off = 32; off > 0; off >>= 1)
        acc += __shfl_down(acc, off, 64);
    __shared__ float wsum[16];
    int lane = threadIdx.x & 63;
    int wid = threadIdx.x >> 6;
    if (lane == 0) wsum[wid] = acc;
    __syncthreads();
    if (threadIdx.x == 0) {
        float total = 0.0f;
        for (int i = 0; i < 16; ++i) total += wsum[i];
        const float log2pi = 1.8378770664093453f;  // log(2*pi)
        out[0] = 0.5f * ((float)NTOK * log2pi + total / (float)BSZ);
    }
}

extern "C" void kernel_launch(void* const* d_in, const int* in_sizes, int n_in,
                              void* d_out, int out_size, void* d_ws, size_t ws_size,
                              hipStream_t stream) {
    const float4* mu = (const float4*)d_in[0];
    const float4* sigma = (const float4*)d_in[1];
    const float4* ty = (const float4*)d_in[2];
    float* out = (float*)d_out;
    float* partials = (float*)d_ws;  // NBLOCKS floats, fully written each call

    gauss_nll_partial<<<NBLOCKS, NTHREADS, 0, stream>>>(mu, sigma, ty, partials);
    gauss_nll_final<<<1, 1024, 0, stream>>>(partials, out);
}